// Round 8
// baseline (50.735 us; speedup 1.0000x reference)
//
#include <hip/hip_runtime.h>
#include <hip/hip_bf16.h>
#include <math.h>

#define NB   32
#define CIN  4
#define COUT 64
#define TT   6
#define VV   512
#define P_OFF (NB*COUT*TT*VV)   // out then p in d_out
#define SPLITS 8
#define CH   (VV/SPLITS)        // 64 softmax rows per block
#define NROW 24                 // c*6+t rows of x per batch
#define E_FLOATS (2*NB*VV)      // e_i + e_j in ws

__device__ inline unsigned int pack2(float a, float b) {
    __hip_bfloat162 h = __float22bfloat162_rn(make_float2(a, b));
    return *reinterpret_cast<unsigned int*>(&h);
}
__device__ inline float blo(unsigned int u) { return __uint_as_float(u << 16); }
__device__ inline float bhi(unsigned int u) { return __uint_as_float(u & 0xffff0000u); }

// ---------------------------------------------------------------------------
// Kernel 1: e_i[n,v], e_j[n,v]  (collapsed xc -> x1 -> e chain)
// ---------------------------------------------------------------------------
__global__ __launch_bounds__(256) void e_kernel(
    const float* __restrict__ x,
    const float* __restrict__ conv_w,
    const float* __restrict__ conv_b,
    const float* __restrict__ l2_w,
    const float* __restrict__ l2_b,
    const float* __restrict__ l1_w,
    float* __restrict__ e)
{
    __shared__ float W1[CIN], W2[CIN], cst[2];
    int tid = threadIdx.x;
    if (tid < CIN) {
        float w1 = 0.f, w2 = 0.f;
        for (int o = 0; o < COUT; ++o) {
            w1 += l1_w[o]        * conv_w[o*CIN + tid];
            w2 += l1_w[COUT + o] * conv_w[o*CIN + tid];
        }
        W1[tid] = w1; W2[tid] = w2;
    }
    if (tid == CIN) {
        float B1 = 0.f, B2 = 0.f, S1 = 0.f, S2 = 0.f;
        for (int o = 0; o < COUT; ++o) {
            B1 += l1_w[o]        * conv_b[o];
            B2 += l1_w[COUT + o] * conv_b[o];
            S1 += l1_w[o];
            S2 += l1_w[COUT + o];
        }
        float Ls = 0.f;
        for (int t = 0; t < TT; ++t) Ls += l2_w[t];
        cst[0] = Ls*B1 + l2_b[0]*S1;
        cst[1] = Ls*B2 + l2_b[0]*S2;
    }
    __syncthreads();

    int idx = blockIdx.x * 256 + tid;      // n*V + v
    int n = idx >> 9, v = idx & (VV-1);
    float ei = cst[0], ej = cst[1];
    #pragma unroll
    for (int c = 0; c < CIN; ++c) {
        float wc1 = W1[c], wc2 = W2[c];
        #pragma unroll
        for (int t = 0; t < TT; ++t) {
            float xv = x[((n*CIN + c)*TT + t)*VV + v];
            float lw = l2_w[t];
            ei += lw*wc1*xv;
            ej += lw*wc2*xv;
        }
    }
    e[idx]         = ei;
    e[NB*VV + idx] = ej;
}

// ---------------------------------------------------------------------------
// Kernel 2 (fused): per block (s,n): 64 softmax rows -> p (f32, global) and
// y_part[r][w] = sum_{i in chunk} x[n,r,i]*p[n,i,w]  (p via bf16x2 LDS).
// 8 waves; 4 subs of 16 rows; wave q computes rows q*2,q*2+1 per sub
// (j = lane*8+m). ALL mask/bias loads preissued at kernel start (16 int4
// in flight per lane) to cover HBM latency. Accumulate: wave q owns x-rows
// q*3..q*3+2, lane owns w = lane*8+m: per (wave,i) 1 b128 p-read +
// 1 broadcast b128 x-read for 24 FMAs; acc[3][8]=24 VGPRs.
// ---------------------------------------------------------------------------
__global__ __launch_bounds__(512, 2) void fused_kernel(
    const float* __restrict__ x,
    const int*   __restrict__ A,
    const float* __restrict__ e,
    const float* __restrict__ l1_b,
    float*       __restrict__ p,
    float*       __restrict__ ypart)
{
    __shared__ float xst[CH][8][4];              // [i][q][rr(0..2),pad] 8 KB
    __shared__ unsigned int ps[2][16][VV/2];     // bf16x2, 2 x 16 KB

    int s = blockIdx.x;                  // 8 chunks of 64 rows
    int n = blockIdx.y;
    int tid = threadIdx.x;
    int lane = tid & 63;
    int q = tid >> 6;                    // wave 0..7

    // stage x slab: xst[i][r/3][r%3]
    for (int l = tid; l < NROW*CH; l += 512) {
        int r = l >> 6, i = l & 63;
        xst[i][r/3][r%3] = x[((size_t)n*NROW + r)*VV + s*CH + i];
    }

    // ---- deep prefetch: ALL mask rows + biases for this block ----
    const int* mbase = A + (size_t)(n*8 + 7)*VV*VV;
    int4 mreg[16];
    float br[8];
    #pragma unroll
    for (int sub = 0; sub < 4; ++sub) {
        int i0 = s*CH + sub*16 + q*2;
        const int* mr = mbase + (size_t)i0*VV + lane*8;
        mreg[sub*4+0] = *(const int4*)mr;
        mreg[sub*4+1] = *(const int4*)(mr + 4);
        mreg[sub*4+2] = *(const int4*)(mr + VV);
        mreg[sub*4+3] = *(const int4*)(mr + VV + 4);
        br[sub*2]   = e[n*VV + i0];
        br[sub*2+1] = e[n*VV + i0 + 1];
    }

    float l1b_val = l1_b[0];
    float4 ej0 = *(const float4*)(e + NB*VV + n*VV + lane*8);
    float4 ej1 = *(const float4*)(e + NB*VV + n*VV + lane*8 + 4);
    float ejv[8] = {ej0.x, ej0.y, ej0.z, ej0.w, ej1.x, ej1.y, ej1.z, ej1.w};

    float acc[3][8];
    #pragma unroll
    for (int rr = 0; rr < 3; ++rr)
        #pragma unroll
        for (int m2 = 0; m2 < 8; ++m2) acc[rr][m2] = 0.f;
    float a24[8] = {0.f,0.f,0.f,0.f,0.f,0.f,0.f,0.f};

    // no initial barrier: xst/ps are first read after the sub-0 barrier

    for (int sub = 0; sub < 4; ++sub) {
        int i_gA = s*CH + sub*16 + q*2;

        // ---- softmax rows A & B from preloaded regs (j = lane*8 + m) ----
        int4 cA0 = mreg[sub*4+0], cA1 = mreg[sub*4+1];
        int4 cB0 = mreg[sub*4+2], cB1 = mreg[sub*4+3];
        float biasA = br[sub*2] + l1b_val, biasB = br[sub*2+1] + l1b_val;

        float svA[8], svB[8];
        int mkA[8] = {cA0.x,cA0.y,cA0.z,cA0.w, cA1.x,cA1.y,cA1.z,cA1.w};
        int mkB[8] = {cB0.x,cB0.y,cB0.z,cB0.w, cB1.x,cB1.y,cB1.z,cB1.w};
        #pragma unroll
        for (int m2 = 0; m2 < 8; ++m2) {
            float tA = biasA + ejv[m2]; tA = (tA >= 0.f) ? tA : 0.2f*tA;
            svA[m2] = (mkA[m2] == 0) ? -INFINITY : tA;
            float tB = biasB + ejv[m2]; tB = (tB >= 0.f) ? tB : 0.2f*tB;
            svB[m2] = (mkB[m2] == 0) ? -INFINITY : tB;
        }
        float mA = svA[0], mB = svB[0];
        #pragma unroll
        for (int m2 = 1; m2 < 8; ++m2) {
            mA = fmaxf(mA, svA[m2]); mB = fmaxf(mB, svB[m2]);
        }
        #pragma unroll
        for (int off = 32; off; off >>= 1) {
            mA = fmaxf(mA, __shfl_xor(mA, off));
            mB = fmaxf(mB, __shfl_xor(mB, off));
        }
        float sumA = 0.f, sumB = 0.f;
        if (mA > -INFINITY) {
            #pragma unroll
            for (int m2 = 0; m2 < 8; ++m2) { svA[m2] = __expf(svA[m2]-mA); sumA += svA[m2]; }
        } else {
            #pragma unroll
            for (int m2 = 0; m2 < 8; ++m2) svA[m2] = 0.f;
        }
        if (mB > -INFINITY) {
            #pragma unroll
            for (int m2 = 0; m2 < 8; ++m2) { svB[m2] = __expf(svB[m2]-mB); sumB += svB[m2]; }
        } else {
            #pragma unroll
            for (int m2 = 0; m2 < 8; ++m2) svB[m2] = 0.f;
        }
        #pragma unroll
        for (int off = 32; off; off >>= 1) {
            sumA += __shfl_xor(sumA, off);
            sumB += __shfl_xor(sumB, off);
        }
        float invA = (sumA > 0.f) ? 1.f/sumA : 0.f;
        float invB = (sumB > 0.f) ? 1.f/sumB : 0.f;

        float pA[8], pB[8];
        #pragma unroll
        for (int m2 = 0; m2 < 8; ++m2) { pA[m2] = svA[m2]*invA; pB[m2] = svB[m2]*invB; }

        // global p stores (f32 exact, 16B/lane coalesced)
        float* prA = p + ((size_t)(n*VV + i_gA))*VV + lane*8;
        float4 pA03 = {pA[0],pA[1],pA[2],pA[3]}, pA47 = {pA[4],pA[5],pA[6],pA[7]};
        float4 pB03 = {pB[0],pB[1],pB[2],pB[3]}, pB47 = {pB[4],pB[5],pB[6],pB[7]};
        *(float4*)prA            = pA03;
        *(float4*)(prA + 4)      = pA47;
        *(float4*)(prA + VV)     = pB03;
        *(float4*)(prA + VV + 4) = pB47;

        // LDS p-row stage, packed bf16x2 (buffer sub&1)
        uint4 ua = {pack2(pA[0],pA[1]), pack2(pA[2],pA[3]),
                    pack2(pA[4],pA[5]), pack2(pA[6],pA[7])};
        uint4 ub = {pack2(pB[0],pB[1]), pack2(pB[2],pB[3]),
                    pack2(pB[4],pB[5]), pack2(pB[6],pB[7])};
        *(uint4*)&ps[sub & 1][q*2    ][lane*4] = ua;
        *(uint4*)&ps[sub & 1][q*2 + 1][lane*4] = ub;

        __syncthreads();   // ps[sub&1] + (sub==0: xst) ready

        // ---- accumulate: wave q = x-rows q*3..+2, lane = w lane*8+m ----
        #pragma unroll
        for (int i = 0; i < 16; ++i) {
            uint4 pu = *(const uint4*)&ps[sub & 1][i][lane*4];
            float4 xq = *(const float4*)&xst[sub*16 + i][q][0];  // broadcast
            float pv[8] = {blo(pu.x), bhi(pu.x), blo(pu.y), bhi(pu.y),
                           blo(pu.z), bhi(pu.z), blo(pu.w), bhi(pu.w)};
            #pragma unroll
            for (int m2 = 0; m2 < 8; ++m2) {
                acc[0][m2] = fmaf(xq.x, pv[m2], acc[0][m2]);
                acc[1][m2] = fmaf(xq.y, pv[m2], acc[1][m2]);
                acc[2][m2] = fmaf(xq.z, pv[m2], acc[2][m2]);
            }
            if (q == 0) {
                #pragma unroll
                for (int m2 = 0; m2 < 8; ++m2) a24[m2] += pv[m2];
            }
        }
        // next sub writes the other ps buffer; this barrier fences reuse
    }

    // ---- write ypart (2 x b128 per row, coalesced) ----
    float* yo = ypart + (size_t)(s*NB + n)*25*VV + lane*8;
    #pragma unroll
    for (int rr = 0; rr < 3; ++rr) {
        int row = q*3 + rr;
        float4 s0 = {acc[rr][0], acc[rr][1], acc[rr][2], acc[rr][3]};
        float4 s1 = {acc[rr][4], acc[rr][5], acc[rr][6], acc[rr][7]};
        *(float4*)(yo + (size_t)row*VV)     = s0;
        *(float4*)(yo + (size_t)row*VV + 4) = s1;
    }
    if (q == 0) {
        float4 s0 = {a24[0], a24[1], a24[2], a24[3]};
        float4 s1 = {a24[4], a24[5], a24[6], a24[7]};
        *(float4*)(yo + (size_t)24*VV)     = s0;
        *(float4*)(yo + (size_t)24*VV + 4) = s1;
    }
}

// ---------------------------------------------------------------------------
// Kernel 3: out[n,o,t,w] = sum_c conv_w[o,c]*y[c*6+t,w] + conv_b[o]*y[24,w]
// Stages + split-reduces ypart through LDS exactly once.
// ---------------------------------------------------------------------------
__global__ __launch_bounds__(256) void expand_kernel(
    const float* __restrict__ ypart,
    const float* __restrict__ conv_w,
    const float* __restrict__ conv_b,
    float*       __restrict__ out)
{
    __shared__ float ysm[25][64];
    __shared__ float wsm[COUT*CIN];
    __shared__ float bsm[COUT];

    int wc = blockIdx.x;                 // 8 w-chunks of 64
    int n  = blockIdx.y;
    int tid = threadIdx.x;

    if (tid < COUT*CIN) wsm[tid] = conv_w[tid];
    if (tid < COUT)     bsm[tid] = conv_b[tid];

    // stage + reduce splits: 25*64 = 1600 floats as 400 float4
    for (int l4 = tid; l4 < 400; l4 += 256) {
        int r = l4 >> 4, w4 = l4 & 15;
        float4 a = {0.f, 0.f, 0.f, 0.f};
        #pragma unroll
        for (int s = 0; s < SPLITS; ++s) {
            float4 v = *(const float4*)(ypart +
                ((size_t)(s*NB + n)*25 + r)*VV + wc*64 + w4*4);
            a.x += v.x; a.y += v.y; a.z += v.z; a.w += v.w;
        }
        *(float4*)&ysm[r][w4*4] = a;
    }
    __syncthreads();

    int w  = tid & 63;
    int og = tid >> 6;                   // 4 groups x 16 o

    float y[25];
    #pragma unroll
    for (int r = 0; r < 25; ++r) y[r] = ysm[r][w];

    #pragma unroll
    for (int oo = 0; oo < 16; ++oo) {
        int o = og*16 + oo;
        float wb[CIN];
        #pragma unroll
        for (int c = 0; c < CIN; ++c) wb[c] = wsm[o*CIN + c];
        float bo = bsm[o];
        #pragma unroll
        for (int t = 0; t < TT; ++t) {
            float val = bo * y[24];
            #pragma unroll
            for (int c = 0; c < CIN; ++c) val = fmaf(wb[c], y[c*TT + t], val);
            out[((size_t)(n*COUT + o)*TT + t)*VV + wc*64 + w] = val;
        }
    }
}

// ---------------------------------------------------------------------------
extern "C" void kernel_launch(void* const* d_in, const int* in_sizes, int n_in,
                              void* d_out, int out_size, void* d_ws, size_t ws_size,
                              hipStream_t stream)
{
    const float* x      = (const float*)d_in[0];
    const int*   A      = (const int*)  d_in[1];
    const float* conv_w = (const float*)d_in[2];
    const float* conv_b = (const float*)d_in[3];
    const float* l2_w   = (const float*)d_in[4];
    const float* l2_b   = (const float*)d_in[5];
    const float* l1_w   = (const float*)d_in[6];
    const float* l1_b   = (const float*)d_in[7];

    float* out = (float*)d_out;
    float* pP  = out + P_OFF;              // p region of d_out
    float* e   = (float*)d_ws;             // 128 KB
    float* yp  = e + E_FLOATS;             // SPLITS*NB*25*VV f32 = 13.1 MB

    e_kernel<<<NB*VV/256, 256, 0, stream>>>(x, conv_w, conv_b, l2_w, l2_b, l1_w, e);

    dim3 gf(SPLITS, NB);                   // 256 blocks x 512 thr
    fused_kernel<<<gf, 512, 0, stream>>>(x, A, e, l1_b, pP, yp);

    dim3 ge(8, NB);                        // 256 blocks
    expand_kernel<<<ge, 256, 0, stream>>>(yp, conv_w, conv_b, out);
}

// Round 9
// 34.616 us; speedup vs baseline: 1.4657x; 1.4657x over previous
//
#include <hip/hip_runtime.h>
#include <hip/hip_bf16.h>
#include <math.h>

#define NB   32
#define CIN  4
#define COUT 64
#define TT   6
#define VV   512
#define P_OFF (NB*COUT*TT*VV)   // out then p in d_out
#define SPLITS 8
#define CH   (VV/SPLITS)        // 64 softmax rows per block
#define NROW 24                 // c*6+t rows of x per batch
#define E_FLOATS (2*NB*VV)      // e_i + e_j in ws
#define PKW  516                // pk row stride (u32), pad for bank spread

typedef __attribute__((ext_vector_type(8))) short bf16x8;
typedef __attribute__((ext_vector_type(4))) float f32x4;

__device__ inline unsigned int pack2(float a, float b) {
    __hip_bfloat162 h = __float22bfloat162_rn(make_float2(a, b));
    return *reinterpret_cast<unsigned int*>(&h);
}

// ---------------------------------------------------------------------------
// Kernel 1: e_i[n,v], e_j[n,v]  (collapsed xc -> x1 -> e chain)
// ---------------------------------------------------------------------------
__global__ __launch_bounds__(256) void e_kernel(
    const float* __restrict__ x,
    const float* __restrict__ conv_w,
    const float* __restrict__ conv_b,
    const float* __restrict__ l2_w,
    const float* __restrict__ l2_b,
    const float* __restrict__ l1_w,
    float* __restrict__ e)
{
    __shared__ float W1[CIN], W2[CIN], cst[2];
    int tid = threadIdx.x;
    if (tid < CIN) {
        float w1 = 0.f, w2 = 0.f;
        for (int o = 0; o < COUT; ++o) {
            w1 += l1_w[o]        * conv_w[o*CIN + tid];
            w2 += l1_w[COUT + o] * conv_w[o*CIN + tid];
        }
        W1[tid] = w1; W2[tid] = w2;
    }
    if (tid == CIN) {
        float B1 = 0.f, B2 = 0.f, S1 = 0.f, S2 = 0.f;
        for (int o = 0; o < COUT; ++o) {
            B1 += l1_w[o]        * conv_b[o];
            B2 += l1_w[COUT + o] * conv_b[o];
            S1 += l1_w[o];
            S2 += l1_w[COUT + o];
        }
        float Ls = 0.f;
        for (int t = 0; t < TT; ++t) Ls += l2_w[t];
        cst[0] = Ls*B1 + l2_b[0]*S1;
        cst[1] = Ls*B2 + l2_b[0]*S2;
    }
    __syncthreads();

    int idx = blockIdx.x * 256 + tid;      // n*V + v
    int n = idx >> 9, v = idx & (VV-1);
    float ei = cst[0], ej = cst[1];
    #pragma unroll
    for (int c = 0; c < CIN; ++c) {
        float wc1 = W1[c], wc2 = W2[c];
        #pragma unroll
        for (int t = 0; t < TT; ++t) {
            float xv = x[((n*CIN + c)*TT + t)*VV + v];
            float lw = l2_w[t];
            ei += lw*wc1*xv;
            ej += lw*wc2*xv;
        }
    }
    e[idx]         = ei;
    e[NB*VV + idx] = ej;
}

// ---------------------------------------------------------------------------
// Kernel 2 (fused, MFMA): per block (s,n): 64 softmax rows -> p (f32 global),
// and y_part[r][w] = sum_i x[n,r,i]*p[n,i,w] via mfma_f32_16x16x32_bf16.
// M=32 (24 x-rows + ones-row for colsum + pad), K=64 (2 K-groups of 32),
// N=512 (8 waves x 4 n-tiles). Softmax: wave q does rows q*2,q*2+1 per
// 16-row sub (j = lane*8+m); packs p-pairs as bf16x2 into pk[16][PKW].
// Per wave: 16 MFMA total; acc = 2x4 f32x4 = 32 VGPR.
// ---------------------------------------------------------------------------
__global__ __launch_bounds__(512, 4) void fused_kernel(
    const float* __restrict__ x,
    const int*   __restrict__ A,
    const float* __restrict__ e,
    const float* __restrict__ l1_b,
    float*       __restrict__ p,
    float*       __restrict__ ypart)
{
    __shared__ float xst[CH][33];            // [i][r], r24 = ones, 25..32 = 0
    __shared__ unsigned int pk[16][PKW];     // bf16-pair stage for one K-group

    int s = blockIdx.x;                  // 8 chunks of 64 rows
    int n = blockIdx.y;
    int tid = threadIdx.x;
    int lane = tid & 63;
    int q = tid >> 6;                    // wave 0..7

    // stage xst[i][r]: coalesced over i (lanes consecutive)
    for (int idx = tid; idx < CH*33; idx += 512) {
        int r = idx >> 6;                // 0..32
        int i = idx & 63;
        float v = 0.f;
        if (r < NROW)       v = x[((size_t)n*NROW + r)*VV + s*CH + i];
        else if (r == NROW) v = 1.f;     // ones-row -> colsum
        xst[i][r] = v;
    }

    float l1b_val = l1_b[0];
    float4 ej0 = *(const float4*)(e + NB*VV + n*VV + lane*8);
    float4 ej1 = *(const float4*)(e + NB*VV + n*VV + lane*8 + 4);
    float ejv[8] = {ej0.x, ej0.y, ej0.z, ej0.w, ej1.x, ej1.y, ej1.z, ej1.w};

    const int* mbase = A + (size_t)(n*8 + 7)*VV*VV;

    f32x4 acc[2][4];
    #pragma unroll
    for (int mt = 0; mt < 2; ++mt)
        #pragma unroll
        for (int t = 0; t < 4; ++t) acc[mt][t] = (f32x4){0.f, 0.f, 0.f, 0.f};

    bf16x8 afr[2][2];                    // [Kgroup][mtile], built after B1

    // prefetch sub 0 masks/biases (one sub ahead thereafter)
    int4 mA0, mA1, mB0, mB1;
    float bA, bB;
    {
        int i0 = s*CH + q*2;
        const int* mr = mbase + (size_t)i0*VV + lane*8;
        mA0 = *(const int4*)mr;       mA1 = *(const int4*)(mr + 4);
        mB0 = *(const int4*)(mr+VV);  mB1 = *(const int4*)(mr + VV + 4);
        bA = e[n*VV + i0]; bB = e[n*VV + i0 + 1];
    }

    for (int sub = 0; sub < 4; ++sub) {
        int i_gA = s*CH + sub*16 + q*2;

        int4 cA0 = mA0, cA1 = mA1, cB0 = mB0, cB1 = mB1;
        float biasA = bA + l1b_val, biasB = bB + l1b_val;

        if (sub < 3) {                   // prefetch next sub
            const int* mr = mbase + (size_t)(i_gA + 16)*VV + lane*8;
            mA0 = *(const int4*)mr;       mA1 = *(const int4*)(mr + 4);
            mB0 = *(const int4*)(mr+VV);  mB1 = *(const int4*)(mr + VV + 4);
            bA = e[n*VV + i_gA + 16]; bB = e[n*VV + i_gA + 17];
        }

        // ---- softmax rows A & B (j = lane*8 + m) ----
        float svA[8], svB[8];
        int mkA[8] = {cA0.x,cA0.y,cA0.z,cA0.w, cA1.x,cA1.y,cA1.z,cA1.w};
        int mkB[8] = {cB0.x,cB0.y,cB0.z,cB0.w, cB1.x,cB1.y,cB1.z,cB1.w};
        #pragma unroll
        for (int m2 = 0; m2 < 8; ++m2) {
            float tA = biasA + ejv[m2]; tA = (tA >= 0.f) ? tA : 0.2f*tA;
            svA[m2] = (mkA[m2] == 0) ? -INFINITY : tA;
            float tB = biasB + ejv[m2]; tB = (tB >= 0.f) ? tB : 0.2f*tB;
            svB[m2] = (mkB[m2] == 0) ? -INFINITY : tB;
        }
        float mA = svA[0], mB = svB[0];
        #pragma unroll
        for (int m2 = 1; m2 < 8; ++m2) {
            mA = fmaxf(mA, svA[m2]); mB = fmaxf(mB, svB[m2]);
        }
        #pragma unroll
        for (int off = 32; off; off >>= 1) {
            mA = fmaxf(mA, __shfl_xor(mA, off));
            mB = fmaxf(mB, __shfl_xor(mB, off));
        }
        float sumA = 0.f, sumB = 0.f;
        if (mA > -INFINITY) {
            #pragma unroll
            for (int m2 = 0; m2 < 8; ++m2) { svA[m2] = __expf(svA[m2]-mA); sumA += svA[m2]; }
        } else {
            #pragma unroll
            for (int m2 = 0; m2 < 8; ++m2) svA[m2] = 0.f;
        }
        if (mB > -INFINITY) {
            #pragma unroll
            for (int m2 = 0; m2 < 8; ++m2) { svB[m2] = __expf(svB[m2]-mB); sumB += svB[m2]; }
        } else {
            #pragma unroll
            for (int m2 = 0; m2 < 8; ++m2) svB[m2] = 0.f;
        }
        #pragma unroll
        for (int off = 32; off; off >>= 1) {
            sumA += __shfl_xor(sumA, off);
            sumB += __shfl_xor(sumB, off);
        }
        float invA = (sumA > 0.f) ? 1.f/sumA : 0.f;
        float invB = (sumB > 0.f) ? 1.f/sumB : 0.f;
        #pragma unroll
        for (int m2 = 0; m2 < 8; ++m2) { svA[m2] *= invA; svB[m2] *= invB; }

        // global p stores (f32 exact, 16B/lane coalesced)
        float* prA = p + ((size_t)(n*VV + i_gA))*VV + lane*8;
        float4 pA03 = {svA[0],svA[1],svA[2],svA[3]}, pA47 = {svA[4],svA[5],svA[6],svA[7]};
        float4 pB03 = {svB[0],svB[1],svB[2],svB[3]}, pB47 = {svB[4],svB[5],svB[6],svB[7]};
        *(float4*)prA            = pA03;
        *(float4*)(prA + 4)      = pA47;
        *(float4*)(prA + VV)     = pB03;
        *(float4*)(prA + VV + 4) = pB47;

        // pk store: pair-row = (sub&1)*8 + q; u32 j = (rowA[j] lo, rowB[j] hi)
        {
            int pr = (sub & 1)*8 + q;
            uint4 u0 = {pack2(svA[0],svB[0]), pack2(svA[1],svB[1]),
                        pack2(svA[2],svB[2]), pack2(svA[3],svB[3])};
            uint4 u1 = {pack2(svA[4],svB[4]), pack2(svA[5],svB[5]),
                        pack2(svA[6],svB[6]), pack2(svA[7],svB[7])};
            *(uint4*)&pk[pr][lane*8]     = u0;
            *(uint4*)&pk[pr][lane*8 + 4] = u1;
        }

        if (sub & 1) {
            __syncthreads();             // K-group pk complete (+ xst @ sub1)

            if (sub == 1) {
                // build A-frags once: k = g*32 + (lane>>4)*8 + j, m = mt*16+(lane&15)
                #pragma unroll
                for (int g = 0; g < 2; ++g)
                    #pragma unroll
                    for (int mt = 0; mt < 2; ++mt) {
                        int r  = mt*16 + (lane & 15);
                        int kb = g*32 + (lane >> 4)*8;
                        union { unsigned int u[4]; bf16x8 v; } ua;
                        #pragma unroll
                        for (int t = 0; t < 4; ++t)
                            ua.u[t] = pack2(xst[kb + 2*t][r], xst[kb + 2*t + 1][r]);
                        afr[g][mt] = ua.v;
                    }
            }

            int g = sub >> 1;            // K-group 0 or 1
            #pragma unroll
            for (int t = 0; t < 4; ++t) {
                int ncol = (q*4 + t)*16 + (lane & 15);
                union { unsigned int u[4]; bf16x8 v; } ub;
                #pragma unroll
                for (int jj = 0; jj < 4; ++jj)
                    ub.u[jj] = pk[(lane >> 4)*4 + jj][ncol];
                acc[0][t] = __builtin_amdgcn_mfma_f32_16x16x32_bf16(afr[g][0], ub.v, acc[0][t], 0, 0, 0);
                acc[1][t] = __builtin_amdgcn_mfma_f32_16x16x32_bf16(afr[g][1], ub.v, acc[1][t], 0, 0, 0);
            }
            if (sub == 1) __syncthreads();   // MFMA g0 done before sub2 overwrites pk
        }
    }

    // ---- write ypart: D row = mt*16 + (lane>>4)*4 + reg, col = ncol ----
    float* yo = ypart + (size_t)(s*NB + n)*25*VV;
    #pragma unroll
    for (int mt = 0; mt < 2; ++mt)
        #pragma unroll
        for (int t = 0; t < 4; ++t) {
            int ncol = (q*4 + t)*16 + (lane & 15);
            #pragma unroll
            for (int reg = 0; reg < 4; ++reg) {
                int row = mt*16 + (lane >> 4)*4 + reg;
                if (row < 25)
                    yo[(size_t)row*VV + ncol] = acc[mt][t][reg];
            }
        }
}

// ---------------------------------------------------------------------------
// Kernel 3: out[n,o,t,w] = sum_c conv_w[o,c]*y[c*6+t,w] + conv_b[o]*y[24,w]
// Stages + split-reduces ypart through LDS exactly once.
// ---------------------------------------------------------------------------
__global__ __launch_bounds__(256) void expand_kernel(
    const float* __restrict__ ypart,
    const float* __restrict__ conv_w,
    const float* __restrict__ conv_b,
    float*       __restrict__ out)
{
    __shared__ float ysm[25][64];
    __shared__ float wsm[COUT*CIN];
    __shared__ float bsm[COUT];

    int wc = blockIdx.x;                 // 8 w-chunks of 64
    int n  = blockIdx.y;
    int tid = threadIdx.x;

    if (tid < COUT*CIN) wsm[tid] = conv_w[tid];
    if (tid < COUT)     bsm[tid] = conv_b[tid];

    // stage + reduce splits: 25*64 = 1600 floats as 400 float4
    for (int l4 = tid; l4 < 400; l4 += 256) {
        int r = l4 >> 4, w4 = l4 & 15;
        float4 a = {0.f, 0.f, 0.f, 0.f};
        #pragma unroll
        for (int s = 0; s < SPLITS; ++s) {
            float4 v = *(const float4*)(ypart +
                ((size_t)(s*NB + n)*25 + r)*VV + wc*64 + w4*4);
            a.x += v.x; a.y += v.y; a.z += v.z; a.w += v.w;
        }
        *(float4*)&ysm[r][w4*4] = a;
    }
    __syncthreads();

    int w  = tid & 63;
    int og = tid >> 6;                   // 4 groups x 16 o

    float y[25];
    #pragma unroll
    for (int r = 0; r < 25; ++r) y[r] = ysm[r][w];

    #pragma unroll
    for (int oo = 0; oo < 16; ++oo) {
        int o = og*16 + oo;
        float wb[CIN];
        #pragma unroll
        for (int c = 0; c < CIN; ++c) wb[c] = wsm[o*CIN + c];
        float bo = bsm[o];
        #pragma unroll
        for (int t = 0; t < TT; ++t) {
            float val = bo * y[24];
            #pragma unroll
            for (int c = 0; c < CIN; ++c) val = fmaf(wb[c], y[c*TT + t], val);
            out[((size_t)(n*COUT + o)*TT + t)*VV + wc*64 + w] = val;
        }
    }
}

// ---------------------------------------------------------------------------
extern "C" void kernel_launch(void* const* d_in, const int* in_sizes, int n_in,
                              void* d_out, int out_size, void* d_ws, size_t ws_size,
                              hipStream_t stream)
{
    const float* x      = (const float*)d_in[0];
    const int*   A      = (const int*)  d_in[1];
    const float* conv_w = (const float*)d_in[2];
    const float* conv_b = (const float*)d_in[3];
    const float* l2_w   = (const float*)d_in[4];
    const float* l2_b   = (const float*)d_in[5];
    const float* l1_w   = (const float*)d_in[6];
    const float* l1_b   = (const float*)d_in[7];

    float* out = (float*)d_out;
    float* pP  = out + P_OFF;              // p region of d_out
    float* e   = (float*)d_ws;             // 128 KB
    float* yp  = e + E_FLOATS;             // SPLITS*NB*25*VV f32 = 13.1 MB

    e_kernel<<<NB*VV/256, 256, 0, stream>>>(x, conv_w, conv_b, l2_w, l2_b, l1_w, e);

    dim3 gf(SPLITS, NB);                   // 256 blocks x 512 thr
    fused_kernel<<<gf, 512, 0, stream>>>(x, A, e, l1_b, pP, yp);

    dim3 ge(8, NB);                        // 256 blocks
    expand_kernel<<<ge, 256, 0, stream>>>(yp, conv_w, conv_b, out);
}